// Round 5
// baseline (180.694 us; speedup 1.0000x reference)
//
#include <hip/hip_runtime.h>
#include <math.h>

// HardTripletLoss: B=4096, D=512, labels in [0,64), margin 0.5, scalar fp32 out.
// R5: single-wave (64-thread) blocks, one 64x64 triangle tile each (2080 blocks),
// NO barriers — global_load_lds double-buffer paced by manual s_waitcnt vmcnt(16)
// (AITER-style pipeline, expressible only without __syncthreads). Finalize fused
// into the last-finishing block via device-scope done counter.
//
// ws layout (floats): [0,4096)=hp, [4096,8192)=hn, [8192,12288)=norms,
//                     [12288]=done(int), [16384, +2M ushorts)=xhi (4 MB)

#define NB 4096
#define ND 512
#define NLAB 64
#define NTILE 2080  // 64x64-tile upper triangle: 64*65/2

typedef __attribute__((ext_vector_type(8))) short short8;
typedef __attribute__((ext_vector_type(4))) float f32x4;

__device__ __forceinline__ ushort bf16rn(float f) {
    unsigned u = __float_as_uint(f);
    u += 0x7FFF + ((u >> 16) & 1);  // round-to-nearest-even
    return (ushort)(u >> 16);
}

__device__ __forceinline__ void gload_lds16(const ushort* g, ushort* l) {
    __builtin_amdgcn_global_load_lds(
        (const __attribute__((address_space(1))) void*)g,
        (__attribute__((address_space(3))) void*)l, 16, 0, 0);
}

// One wave per row: fp32->bf16 convert + exact fp32 norm; init hp/hn; zero done.
__global__ __launch_bounds__(256) void k_prep(const float* __restrict__ x,
                                              ushort* __restrict__ xhi,
                                              float* __restrict__ norms,
                                              float* __restrict__ hp,
                                              float* __restrict__ hn,
                                              int* __restrict__ done) {
    const int wave = threadIdx.x >> 6, lane = threadIdx.x & 63;
    const int row = blockIdx.x * 4 + wave;
    const float* p = x + (size_t)row * ND + lane * 8;
    float4 v0 = *(const float4*)p;
    float4 v1 = *(const float4*)(p + 4);
    ushort h[8];
    h[0] = bf16rn(v0.x); h[1] = bf16rn(v0.y); h[2] = bf16rn(v0.z); h[3] = bf16rn(v0.w);
    h[4] = bf16rn(v1.x); h[5] = bf16rn(v1.y); h[6] = bf16rn(v1.z); h[7] = bf16rn(v1.w);
    *(uint4*)(xhi + (size_t)row * ND + lane * 8) = *(const uint4*)h;
    float s = v0.x*v0.x + v0.y*v0.y + v0.z*v0.z + v0.w*v0.w
            + v1.x*v1.x + v1.y*v1.y + v1.z*v1.z + v1.w*v1.w;
    #pragma unroll
    for (int m = 1; m < 64; m <<= 1) s += __shfl_xor(s, m);
    if (lane == 0) norms[row] = s;
    if (threadIdx.x < 4) {
        hp[blockIdx.x * 4 + threadIdx.x] = 0.0f;
        hn[blockIdx.x * 4 + threadIdx.x] = __int_as_float(0x7F800000);
    }
    if (blockIdx.x == 0 && threadIdx.x == 0) *done = 0;
}

// 64x64 tile per single-wave block, upper triangle (c>=r). 4x4 tiles of
// mfma_f32_16x16x32_bf16, BK=64 double-buffered via global_load_lds(16B) with
// XOR chunk swizzle (phys = logical ^ (row&7)) -> 0 read conflicts. No barriers:
// pacing by s_waitcnt vmcnt(16) (current buffer's 16 loads are the oldest).
__global__ __launch_bounds__(64, 3) void k_dist(const ushort* __restrict__ xhi,
                                                const int* __restrict__ labels,
                                                const float* __restrict__ norms,
                                                float* __restrict__ hp,
                                                float* __restrict__ hn,
                                                int* __restrict__ done,
                                                float* __restrict__ out) {
    __shared__ ushort As0[64 * 64], As1[64 * 64];  // 8 KB each, row stride 128 B
    __shared__ ushort Bs0[64 * 64], Bs1[64 * 64];

    // Triangular decode: bid -> (r, c), c >= r, 64x64 tile grid.
    const int bid = blockIdx.x;
    int r = (int)((129.0f - sqrtf(16641.0f - 8.0f * (float)bid)) * 0.5f);
    int base = r * 64 - (r * (r - 1)) / 2;
    if (bid < base)                  { --r; base = r * 64 - (r * (r - 1)) / 2; }
    else if (bid >= base + 64 - r)   { ++r; base = r * 64 - (r * (r - 1)) / 2; }
    const int rb = r * 64;
    const int cb = (r + (bid - base)) * 64;
    const bool diag = (rb == cb);

    const int lane = threadIdx.x;
    const int q = lane >> 4, fr = lane & 15;
    const int srow8 = lane >> 3;               // row within each 8-row group
    const int sch = (lane & 7) ^ srow8;        // swizzled source k-chunk

    const ushort* gA = xhi + (size_t)(rb + srow8) * ND + sch * 8;
    const ushort* gB = xhi + (size_t)(cb + srow8) * ND + sch * 8;

    f32x4 acc[4][4];
    #pragma unroll
    for (int mi = 0; mi < 4; ++mi)
        #pragma unroll
        for (int ni = 0; ni < 4; ++ni)
            acc[mi][ni] = (f32x4){0.f, 0.f, 0.f, 0.f};

    // 16 loads per STAGE: 8 for A (8 rows each), 8 for B.
    #define STAGE(At, Bt, kb)                                                  \
        {                                                                      \
            _Pragma("unroll")                                                  \
            for (int t = 0; t < 8; ++t) {                                      \
                gload_lds16(gA + (size_t)(t * 8) * ND + (kb), (At) + t * 8 * 64); \
                gload_lds16(gB + (size_t)(t * 8) * ND + (kb), (Bt) + t * 8 * 64); \
            }                                                                  \
        }

    #define COMPUTE(At, Bt)                                                    \
        {                                                                      \
            _Pragma("unroll")                                                  \
            for (int kk = 0; kk < 2; ++kk) {                                   \
                short8 a[4], b[4];                                             \
                _Pragma("unroll")                                              \
                for (int mi = 0; mi < 4; ++mi) {                               \
                    const int R = mi * 16 + fr;                                \
                    const int pc = ((kk << 2) | q) ^ (R & 7);                  \
                    a[mi] = *(const short8*)((At) + R * 64 + pc * 8);          \
                }                                                              \
                _Pragma("unroll")                                              \
                for (int ni = 0; ni < 4; ++ni) {                               \
                    const int R = ni * 16 + fr;                                \
                    const int pc = ((kk << 2) | q) ^ (R & 7);                  \
                    b[ni] = *(const short8*)((Bt) + R * 64 + pc * 8);          \
                }                                                              \
                _Pragma("unroll")                                              \
                for (int mi = 0; mi < 4; ++mi)                                 \
                    _Pragma("unroll")                                          \
                    for (int ni = 0; ni < 4; ++ni)                             \
                        acc[mi][ni] = __builtin_amdgcn_mfma_f32_16x16x32_bf16( \
                            a[mi], b[ni], acc[mi][ni], 0, 0, 0);               \
            }                                                                  \
        }

    STAGE(As0, Bs0, 0)
    #pragma unroll
    for (int kb = 0; kb < 8; ++kb) {
        if (kb < 7) {
            if (kb & 1) STAGE(As0, Bs0, (kb + 1) * 64)
            else        STAGE(As1, Bs1, (kb + 1) * 64)
            // Current buffer's 16 loads are older than the 16 just issued;
            // vmcnt retires in order, so <=16 outstanding => current buffer ready.
            asm volatile("s_waitcnt vmcnt(16)" ::: "memory");
        } else {
            asm volatile("s_waitcnt vmcnt(0)" ::: "memory");
        }
        if (kb & 1) COMPUTE(As1, Bs1)
        else        COMPUTE(As0, Bs0)
    }
    #undef STAGE
    #undef COMPUTE

    // Epilogue. C/D layout: col = lane&15, row = (lane>>4)*4 + reg.
    int gcol[4]; float ncol[4]; int lcol[4];
    #pragma unroll
    for (int ni = 0; ni < 4; ++ni) {
        gcol[ni] = cb + ni * 16 + fr;
        ncol[ni] = norms[gcol[ni]];
        lcol[ni] = labels[gcol[ni]];
    }
    float pmc[4], nmc[4];
    #pragma unroll
    for (int ni = 0; ni < 4; ++ni) {
        pmc[ni] = 0.0f;
        nmc[ni] = __int_as_float(0x7F800000);
    }
    #pragma unroll
    for (int mi = 0; mi < 4; ++mi) {
        #pragma unroll
        for (int reg = 0; reg < 4; ++reg) {
            const int grow = rb + mi * 16 + q * 4 + reg;
            const float nr = norms[grow];
            const int lr = labels[grow];
            float pm = 0.0f, nm = __int_as_float(0x7F800000);
            #pragma unroll
            for (int ni = 0; ni < 4; ++ni) {
                float sq = fmaxf(nr + ncol[ni] - 2.0f * acc[mi][ni][reg], 0.0f);
                float dd = sqrtf(sq);
                if (lr == lcol[ni]) {
                    if (grow != gcol[ni]) {
                        pm = fmaxf(pm, dd);
                        pmc[ni] = fmaxf(pmc[ni], dd);
                    }
                } else {
                    nm = fminf(nm, dd);
                    nmc[ni] = fminf(nmc[ni], dd);
                }
            }
            #pragma unroll
            for (int m = 1; m <= 8; m <<= 1) {
                pm = fmaxf(pm, __shfl_xor(pm, m));
                nm = fminf(nm, __shfl_xor(nm, m));
            }
            if (fr == 0) {
                atomicMax((int*)&hp[grow], __float_as_int(pm));
                atomicMin((int*)&hn[grow], __float_as_int(nm));
            }
        }
    }
    if (!diag) {  // diagonal tiles: col stats duplicate row stats by symmetry
        #pragma unroll
        for (int ni = 0; ni < 4; ++ni) {
            #pragma unroll
            for (int m = 16; m <= 32; m <<= 1) {
                pmc[ni] = fmaxf(pmc[ni], __shfl_xor(pmc[ni], m));
                nmc[ni] = fminf(nmc[ni], __shfl_xor(nmc[ni], m));
            }
            if (q == 0) {
                atomicMax((int*)&hp[gcol[ni]], __float_as_int(pmc[ni]));
                atomicMin((int*)&hn[gcol[ni]], __float_as_int(nmc[ni]));
            }
        }
    }

    // Last-block finalize: release fence + counter; winner acquires and reduces.
    __threadfence();
    int lastFlag = 0;
    if (lane == 0) lastFlag = (atomicAdd(done, 1) == NTILE - 1) ? 1 : 0;
    lastFlag = __builtin_amdgcn_readfirstlane(lastFlag);
    if (lastFlag) {
        __threadfence();  // acquire side
        __shared__ int h[NLAB];
        h[lane] = 0;  // lane < 64 == NLAB; single wave: program order suffices
        for (int i = lane; i < NB; i += 64) atomicAdd(&h[labels[i]], 1);
        float s = 0.0f;
        int c = 0;
        for (int i = lane; i < NB; i += 64) {
            const int k = h[labels[i]];
            if (k >= 2 && k < NB) {
                float a = __hip_atomic_load(&hp[i], __ATOMIC_RELAXED, __HIP_MEMORY_SCOPE_AGENT);
                float b = __hip_atomic_load(&hn[i], __ATOMIC_RELAXED, __HIP_MEMORY_SCOPE_AGENT);
                s += fmaxf(a - b + 0.5f, 0.0f);
                c += 1;
            }
        }
        #pragma unroll
        for (int m = 1; m < 64; m <<= 1) {
            s += __shfl_xor(s, m);
            c += __shfl_xor(c, m);
        }
        if (lane == 0) out[0] = (c > 0) ? (s / (float)c) : 0.0f;
    }
}

extern "C" void kernel_launch(void* const* d_in, const int* in_sizes, int n_in,
                              void* d_out, int out_size, void* d_ws, size_t ws_size,
                              hipStream_t stream) {
    const float* x      = (const float*)d_in[0];
    const int*   labels = (const int*)d_in[1];
    float* ws    = (float*)d_ws;
    float* hp    = ws;
    float* hn    = ws + NB;
    float* norms = ws + 2 * NB;
    int*   done  = (int*)(ws + 3 * NB);
    ushort* xhi  = (ushort*)(ws + 4 * NB);   // 4 MB bf16 matrix
    float* out   = (float*)d_out;

    k_prep<<<dim3(NB / 4), dim3(256), 0, stream>>>(x, xhi, norms, hp, hn, done);
    k_dist<<<dim3(NTILE), dim3(64), 0, stream>>>(xhi, labels, norms, hp, hn, done, out);
}

// Round 6
// 150.713 us; speedup vs baseline: 1.1989x; 1.1989x over previous
//
#include <hip/hip_runtime.h>
#include <math.h>

// HardTripletLoss: B=4096, D=512, labels in [0,64), margin 0.5, scalar fp32 out.
// R6: single-wave (64-thread) blocks, 64x64 triangle tile each (2080 blocks),
// SINGLE-buffered LDS (16 KB -> 9 blocks/CU resident) with register-level frag
// prefetch: vmcnt(0) -> 16x ds_read_b128 -> lgkmcnt(0) -> stage next tile into
// same LDS -> 32 MFMAs. Barrier-free; finalize fused via device done-counter.
//
// ws layout (floats): [0,4096)=hp, [4096,8192)=hn, [8192,12288)=norms,
//                     [12288]=done(int), [16384, +2M ushorts)=xhi (4 MB)

#define NB 4096
#define ND 512
#define NLAB 64
#define NTILE 2080  // 64x64-tile upper triangle: 64*65/2

typedef __attribute__((ext_vector_type(8))) short short8;
typedef __attribute__((ext_vector_type(4))) float f32x4;

__device__ __forceinline__ ushort bf16rn(float f) {
    unsigned u = __float_as_uint(f);
    u += 0x7FFF + ((u >> 16) & 1);  // round-to-nearest-even
    return (ushort)(u >> 16);
}

__device__ __forceinline__ void gload_lds16(const ushort* g, ushort* l) {
    __builtin_amdgcn_global_load_lds(
        (const __attribute__((address_space(1))) void*)g,
        (__attribute__((address_space(3))) void*)l, 16, 0, 0);
}

// One wave per row: fp32->bf16 convert + exact fp32 norm; init hp/hn; zero done.
__global__ __launch_bounds__(256) void k_prep(const float* __restrict__ x,
                                              ushort* __restrict__ xhi,
                                              float* __restrict__ norms,
                                              float* __restrict__ hp,
                                              float* __restrict__ hn,
                                              int* __restrict__ done) {
    const int wave = threadIdx.x >> 6, lane = threadIdx.x & 63;
    const int row = blockIdx.x * 4 + wave;
    const float* p = x + (size_t)row * ND + lane * 8;
    float4 v0 = *(const float4*)p;
    float4 v1 = *(const float4*)(p + 4);
    ushort h[8];
    h[0] = bf16rn(v0.x); h[1] = bf16rn(v0.y); h[2] = bf16rn(v0.z); h[3] = bf16rn(v0.w);
    h[4] = bf16rn(v1.x); h[5] = bf16rn(v1.y); h[6] = bf16rn(v1.z); h[7] = bf16rn(v1.w);
    *(uint4*)(xhi + (size_t)row * ND + lane * 8) = *(const uint4*)h;
    float s = v0.x*v0.x + v0.y*v0.y + v0.z*v0.z + v0.w*v0.w
            + v1.x*v1.x + v1.y*v1.y + v1.z*v1.z + v1.w*v1.w;
    #pragma unroll
    for (int m = 1; m < 64; m <<= 1) s += __shfl_xor(s, m);
    if (lane == 0) norms[row] = s;
    if (threadIdx.x < 4) {
        hp[blockIdx.x * 4 + threadIdx.x] = 0.0f;
        hn[blockIdx.x * 4 + threadIdx.x] = __int_as_float(0x7F800000);
    }
    if (blockIdx.x == 0 && threadIdx.x == 0) *done = 0;
}

// 64x64 tile per single-wave block, upper triangle (c>=r). 4x4 MFMA tiles of
// 16x16x32 bf16, BK=64, single LDS buffer + register frag prefetch. XOR chunk
// swizzle (phys = logical ^ (row&7)) at the staging SOURCE address -> 0 read
// conflicts. Pipeline order pinned with inline-asm waitcnts (memory clobber).
__global__ __launch_bounds__(64, 2) void k_dist(const ushort* __restrict__ xhi,
                                                const int* __restrict__ labels,
                                                const float* __restrict__ norms,
                                                float* __restrict__ hp,
                                                float* __restrict__ hn,
                                                int* __restrict__ done,
                                                float* __restrict__ out) {
    __shared__ ushort As[64 * 64];  // 8 KB, row stride 128 B
    __shared__ ushort Bs[64 * 64];  // 8 KB

    // Triangular decode: bid -> (r, c), c >= r, 64x64 tile grid.
    const int bid = blockIdx.x;
    int r = (int)((129.0f - sqrtf(16641.0f - 8.0f * (float)bid)) * 0.5f);
    int base = r * 64 - (r * (r - 1)) / 2;
    if (bid < base)                  { --r; base = r * 64 - (r * (r - 1)) / 2; }
    else if (bid >= base + 64 - r)   { ++r; base = r * 64 - (r * (r - 1)) / 2; }
    const int rb = r * 64;
    const int cb = (r + (bid - base)) * 64;
    const bool diag = (rb == cb);

    const int lane = threadIdx.x;
    const int q = lane >> 4, fr = lane & 15;
    const int srow8 = lane >> 3;               // row within each 8-row group
    const int sch = (lane & 7) ^ srow8;        // swizzled source k-chunk

    const ushort* gA = xhi + (size_t)(rb + srow8) * ND + sch * 8;
    const ushort* gB = xhi + (size_t)(cb + srow8) * ND + sch * 8;

    f32x4 acc[4][4];
    #pragma unroll
    for (int mi = 0; mi < 4; ++mi)
        #pragma unroll
        for (int ni = 0; ni < 4; ++ni)
            acc[mi][ni] = (f32x4){0.f, 0.f, 0.f, 0.f};

    // 16 loads per STAGE: 8 for A (8 rows each), 8 for B.
    #define STAGE(kb)                                                          \
        {                                                                      \
            _Pragma("unroll")                                                  \
            for (int t = 0; t < 8; ++t) {                                      \
                gload_lds16(gA + (size_t)(t * 8) * ND + (kb), As + t * 8 * 64); \
                gload_lds16(gB + (size_t)(t * 8) * ND + (kb), Bs + t * 8 * 64); \
            }                                                                  \
        }

    STAGE(0)
    for (int kb = 0; kb < 8; ++kb) {
        // Tile kb fully landed in LDS (staged one iteration ago).
        asm volatile("s_waitcnt vmcnt(0)" ::: "memory");
        short8 a[2][4], b[2][4];
        #pragma unroll
        for (int kk = 0; kk < 2; ++kk) {
            #pragma unroll
            for (int mi = 0; mi < 4; ++mi) {
                const int Ra = mi * 16 + fr;
                const int pa = ((kk << 2) | q) ^ (Ra & 7);
                a[kk][mi] = *(const short8*)(As + Ra * 64 + pa * 8);
                b[kk][mi] = *(const short8*)(Bs + Ra * 64 + pa * 8);
            }
        }
        // All frags in registers -> LDS buffer is dead; safe to overwrite.
        asm volatile("s_waitcnt lgkmcnt(0)" ::: "memory");
        if (kb < 7) STAGE((kb + 1) * 64)
        #pragma unroll
        for (int kk = 0; kk < 2; ++kk)
            #pragma unroll
            for (int mi = 0; mi < 4; ++mi)
                #pragma unroll
                for (int ni = 0; ni < 4; ++ni)
                    acc[mi][ni] = __builtin_amdgcn_mfma_f32_16x16x32_bf16(
                        a[kk][mi], b[kk][ni], acc[mi][ni], 0, 0, 0);
    }
    #undef STAGE

    // Epilogue. C/D layout: col = lane&15, row = (lane>>4)*4 + reg.
    int gcol[4]; float ncol[4]; int lcol[4];
    #pragma unroll
    for (int ni = 0; ni < 4; ++ni) {
        gcol[ni] = cb + ni * 16 + fr;
        ncol[ni] = norms[gcol[ni]];
        lcol[ni] = labels[gcol[ni]];
    }
    float pmc[4], nmc[4];
    #pragma unroll
    for (int ni = 0; ni < 4; ++ni) {
        pmc[ni] = 0.0f;
        nmc[ni] = __int_as_float(0x7F800000);
    }
    #pragma unroll
    for (int mi = 0; mi < 4; ++mi) {
        #pragma unroll
        for (int reg = 0; reg < 4; ++reg) {
            const int grow = rb + mi * 16 + q * 4 + reg;
            const float nr = norms[grow];
            const int lr = labels[grow];
            float pm = 0.0f, nm = __int_as_float(0x7F800000);
            #pragma unroll
            for (int ni = 0; ni < 4; ++ni) {
                float sq = fmaxf(nr + ncol[ni] - 2.0f * acc[mi][ni][reg], 0.0f);
                float dd = sqrtf(sq);
                if (lr == lcol[ni]) {
                    if (grow != gcol[ni]) {
                        pm = fmaxf(pm, dd);
                        pmc[ni] = fmaxf(pmc[ni], dd);
                    }
                } else {
                    nm = fminf(nm, dd);
                    nmc[ni] = fminf(nmc[ni], dd);
                }
            }
            #pragma unroll
            for (int m = 1; m <= 8; m <<= 1) {
                pm = fmaxf(pm, __shfl_xor(pm, m));
                nm = fminf(nm, __shfl_xor(nm, m));
            }
            if (fr == 0) {
                atomicMax((int*)&hp[grow], __float_as_int(pm));
                atomicMin((int*)&hn[grow], __float_as_int(nm));
            }
        }
    }
    if (!diag) {  // diagonal tiles: col stats duplicate row stats by symmetry
        #pragma unroll
        for (int ni = 0; ni < 4; ++ni) {
            #pragma unroll
            for (int m = 16; m <= 32; m <<= 1) {
                pmc[ni] = fmaxf(pmc[ni], __shfl_xor(pmc[ni], m));
                nmc[ni] = fminf(nmc[ni], __shfl_xor(nmc[ni], m));
            }
            if (q == 0) {
                atomicMax((int*)&hp[gcol[ni]], __float_as_int(pmc[ni]));
                atomicMin((int*)&hn[gcol[ni]], __float_as_int(nmc[ni]));
            }
        }
    }

    // Last-block finalize: release fence + counter; winner acquires and reduces.
    __threadfence();
    int lastFlag = 0;
    if (lane == 0) lastFlag = (atomicAdd(done, 1) == NTILE - 1) ? 1 : 0;
    lastFlag = __builtin_amdgcn_readfirstlane(lastFlag);
    if (lastFlag) {
        __threadfence();  // acquire side
        __shared__ int h[NLAB];
        h[lane] = 0;  // lane < 64 == NLAB; single wave: program order suffices
        for (int i = lane; i < NB; i += 64) atomicAdd(&h[labels[i]], 1);
        float s = 0.0f;
        int c = 0;
        for (int i = lane; i < NB; i += 64) {
            const int k = h[labels[i]];
            if (k >= 2 && k < NB) {
                float av = __hip_atomic_load(&hp[i], __ATOMIC_RELAXED, __HIP_MEMORY_SCOPE_AGENT);
                float bv = __hip_atomic_load(&hn[i], __ATOMIC_RELAXED, __HIP_MEMORY_SCOPE_AGENT);
                s += fmaxf(av - bv + 0.5f, 0.0f);
                c += 1;
            }
        }
        #pragma unroll
        for (int m = 1; m < 64; m <<= 1) {
            s += __shfl_xor(s, m);
            c += __shfl_xor(c, m);
        }
        if (lane == 0) out[0] = (c > 0) ? (s / (float)c) : 0.0f;
    }
}

extern "C" void kernel_launch(void* const* d_in, const int* in_sizes, int n_in,
                              void* d_out, int out_size, void* d_ws, size_t ws_size,
                              hipStream_t stream) {
    const float* x      = (const float*)d_in[0];
    const int*   labels = (const int*)d_in[1];
    float* ws    = (float*)d_ws;
    float* hp    = ws;
    float* hn    = ws + NB;
    float* norms = ws + 2 * NB;
    int*   done  = (int*)(ws + 3 * NB);
    ushort* xhi  = (ushort*)(ws + 4 * NB);   // 4 MB bf16 matrix
    float* out   = (float*)d_out;

    k_prep<<<dim3(NB / 4), dim3(256), 0, stream>>>(x, xhi, norms, hp, hn, done);
    k_dist<<<dim3(NTILE), dim3(64), 0, stream>>>(xhi, labels, norms, hp, hn, done, out);
}